// Round 9
// baseline (2667.669 us; speedup 1.0000x reference)
//
#include <hip/hip_runtime.h>
#include <cstdint>
#include <cstddef>

typedef _Float16 f16;
typedef _Float16 f16x8 __attribute__((ext_vector_type(8)));
typedef float f32x4 __attribute__((ext_vector_type(4)));
typedef unsigned u32x4 __attribute__((ext_vector_type(4)));

#define T_  256
#define U_  1024

// ---- workspace offsets (bytes) ----
#define WS_HHI  4096u                     // h plane [128][1024] f16, LINEAR, tagged
#define WS_RH   266240u                   // rh plane [128][1024] f16, LINEAR, tagged
#define WS_WT   528384u                   // recurrent_kernel^T f16 [4096][1024]
#define WS_KDT  8916992u                  // kernel_d^T f16 [4096][128]
#define WS_KST  9965568u                  // kernel_s^T f16 [4096][128]
#define WS_A    11014144u                 // A [128][256][256] f16
#define WS_END  27791360u

// ---- LDS ----
#define L_STHI 0        // staged h (rh in ph2): [16][2048B], swizzled at LDS-write
#define L_ABUF 32768    // A(t+1) slice [16][512B] swizzled
#define L_EXCH 40960    // 24 tiles x 1040B
#define L_Z    65920    // [16][32] f32
#define L_LB   67968    // base dbuf: 2 x [16 rows][4 reg][32 cols] f32
#define L_PACK 84352    // 1KB pack buffer [16 rows][64B]
#define LDS_SZ 85376
#define EXT(kq,ch,q) (L_EXCH + (((kq)*2+(ch))*3+(q))*1040)

#define POLL_BOUND (1 << 18)

#define MFMA16(a,b,c) __builtin_amdgcn_mfma_f32_16x16x32_f16((a),(b),(c),0,0,0)
__device__ __forceinline__ float sigm(float v) { return 1.0f / (1.0f + __expf(-v)); }
__device__ __forceinline__ void vwait0() { asm volatile("s_waitcnt vmcnt(0)" ::: "memory"); }

// ---- system-scope (MALL coherence point) data ops ----
__device__ __forceinline__ void gload_x4(f16x8& d, const void* p) {
  asm volatile("global_load_dwordx4 %0, %1, off sc0 sc1" : "=&v"(d) : "v"(p));
}
__device__ __forceinline__ void gstore_x4(void* p, f16x8 v) {
  asm volatile("global_store_dwordx4 %0, %1, off sc0 sc1" :: "v"(p), "v"(v) : "memory");
}
// chunk valid iff ALL 8 f16 low bits == tag (dword atomicity makes tearing visible)
__device__ __forceinline__ bool chunk_ok(f16x8 v, unsigned tag) {
  u32x4 d = __builtin_bit_cast(u32x4, v);
  if (tag) { unsigned a = d[0] & d[1] & d[2] & d[3]; return (a & 0x10001u) == 0x10001u; }
  unsigned o = d[0] | d[1] | d[2] | d[3];
  return (o & 0x10001u) == 0u;
}
// force low-bit tag into an f16
__device__ __forceinline__ unsigned short tag16(float x, unsigned tag) {
  unsigned short us = __builtin_bit_cast(unsigned short, (f16)x);
  return (unsigned short)((us & 0xFFFEu) | tag);
}

// ---------- prep: weight transposes ----------
__global__ __launch_bounds__(256) void prep_kernel(const float* __restrict__ rk,
                                                   const float* __restrict__ kd,
                                                   const float* __restrict__ ks,
                                                   f16* __restrict__ wT,
                                                   f16* __restrict__ kdT,
                                                   f16* __restrict__ ksT) {
  size_t i = (size_t)blockIdx.x * 256 + threadIdx.x;
  if (i < 4194304u) {
    int k = (int)(i >> 12), n = (int)(i & 4095);
    wT[(size_t)n * 1024 + k] = (f16)rk[i];
  } else if (i < 4718592u) {
    size_t j = i - 4194304u;
    int k = (int)(j >> 12), n = (int)(j & 4095);
    kdT[(size_t)n * 128 + k] = (f16)kd[j];
  } else {
    size_t j = i - 4718592u;
    int k = (int)(j >> 12), n = (int)(j & 4095);
    ksT[(size_t)n * 128 + k] = (f16)ks[j];
  }
}

// ---------- prep: A = [tanh(d@Wd+bd) | tanh(s@Ws+bs)], d = cumsum ----------
__global__ __launch_bounds__(64) void acum_kernel(const float* __restrict__ x,
    const float* __restrict__ Wd, const float* __restrict__ bd,
    const float* __restrict__ Ws, const float* __restrict__ bs,
    f16* __restrict__ A) {
  const int b = blockIdx.x, lane = threadIdx.x;
  float w0[4], w1[4], w2[4], bb[4];
  #pragma unroll
  for (int q = 0; q < 4; ++q) {
    int col = lane + 64 * q;
    if (col < 128) { w0[q] = Wd[col]; w1[q] = Wd[128 + col]; w2[q] = 0.f; bb[q] = bd[col]; }
    else { int c2 = col - 128; w0[q] = Ws[c2]; w1[q] = Ws[128 + c2]; w2[q] = Ws[256 + c2]; bb[q] = bs[c2]; }
  }
  float d0 = 0.f, d1 = 0.f;
  for (int t = 0; t < T_; ++t) {
    const float* xp = x + ((size_t)b * T_ + t) * 5;
    float x0 = xp[0], x1 = xp[1], x2 = xp[2], x3 = xp[3], x4 = xp[4];
    d0 += x0; d1 += x1;
    f16* Ap = A + ((size_t)b * T_ + t) * 256;
    #pragma unroll
    for (int q = 0; q < 4; ++q) {
      int col = lane + 64 * q;
      float v = (col < 128) ? tanhf(d0 * w0[q] + d1 * w1[q] + bb[q])
                            : tanhf(x2 * w0[q] + x3 * w1[q] + x4 * w2[q] + bb[q]);
      Ap[col] = (f16)v;
    }
  }
}

// ---------- persistent SGRU: 256 blocks = 8 rg (16 rows) x 32 c (32 cols/region) ----------
__global__ __launch_bounds__(512) void sgru_kernel(
    const int* __restrict__ chp, const float* __restrict__ kcp,
    const float* __restrict__ bias, char* __restrict__ wsb,
    float* __restrict__ out) {
  extern __shared__ char lds[];
  const int tid  = threadIdx.x;
  const int wid  = tid >> 6;
  const int lane = tid & 63;
  const int lcol = lane & 15;
  const int kc   = lane >> 4;
  const int lin  = blockIdx.x;
  const int rg   = lin >> 5;
  const int c    = lin & 31;
  const int row0 = rg * 16;
  const int kq   = wid >> 1;        // k-quarter 0..3
  const int chh  = wid & 1;         // 16-col half 0..1
  // reduce mapping: 512 threads -> (rch, rm, rl)
  const int rp = tid & 255, rm = rp >> 4, rl = rp & 15, rch = tid >> 8;
  const int rucol = 32 * c + 16 * rch + rl;
  // base tile per wave
  const int wreg = wid >> 1, wch = wid & 1;
  const int bcolw = wreg * 1024 + 32 * c + 16 * wch + lcol;

  const f16* __restrict__ wT  = (const f16*)(wsb + WS_WT);
  const f16* __restrict__ kdT = (const f16*)(wsb + WS_KDT);
  const f16* __restrict__ ksT = (const f16*)(wsb + WS_KST);
  const f16* __restrict__ Ap  = (const f16*)(wsb + WS_A);

  // ---- resident B fragments ----
  f16x8 Bp1[3][8], BpB[8];
  #pragma unroll
  for (int q = 0; q < 3; ++q) {
    const int orig = (q == 2 ? 3072 : q * 1024) + 32 * c + 16 * chh + lcol;
    const f16* wp = wT + (size_t)orig * 1024;
    #pragma unroll
    for (int j = 0; j < 8; ++j)
      Bp1[q][j] = *(const f16x8*)(wp + (kq * 8 + j) * 32 + kc * 8);
  }
  #pragma unroll
  for (int j = 0; j < 8; ++j)
    BpB[j] = (j < 4) ? *(const f16x8*)(kdT + (size_t)bcolw * 128 + j * 32 + kc * 8)
                     : *(const f16x8*)(ksT + (size_t)bcolw * 128 + (j - 4) * 32 + kc * 8);
  const float biasv = bias[bcolw];
  float h_own = 0.f;
  int chreg[4]; float kcv[4];

  // ---- pre-loop: stage A(0); kc(0) gathers; chreg = ch(1); base(0) -> LB[0] ----
  {
    f16x8 av = *(const f16x8*)(Ap + ((size_t)(row0 + (tid >> 5)) * T_ + 0) * 256 + (tid & 31) * 8);
    *(f16x8*)(lds + L_ABUF + (tid >> 5) * 512 + (((tid & 31) * 16) ^ (((tid >> 5) & 7) << 4))) = av;
  }
  #pragma unroll
  for (int e = 0; e < 4; ++e) {
    const size_t r = (size_t)(row0 + kc * 4 + e) * T_;
    kcv[e] = kcp[(size_t)chp[r] * 4096 + bcolw];
    chreg[e] = chp[r + 1];
  }
  __syncthreads();
  {
    f32x4 ab = {0.f, 0.f, 0.f, 0.f};
    #pragma unroll
    for (int j = 0; j < 8; ++j) {
      f16x8 a = *(f16x8*)(lds + L_ABUF + lcol * 512 + ((j * 64 + kc * 16) ^ ((lcol & 7) << 4)));
      ab = MFMA16(a, BpB[j], ab);
    }
    float* lb0 = (float*)(lds + L_LB);
    #pragma unroll
    for (int e = 0; e < 4; ++e)
      lb0[((kc * 4 + e) * 4 + wreg) * 32 + 16 * wch + lcol] = ab[e] + kcv[e] + biasv;
  }
  __syncthreads();

  for (int t = 0; ; ++t) {
    const int p = t & 1;
    const unsigned htag = (unsigned)(t & 1);        // h(t) tag
    const unsigned ntag = (unsigned)((t + 1) & 1);  // rh(t) and h(t+1) tag
    float* LBp = (float*)(lds + L_LB + p * 8192);        // base(t)
    float* LBq = (float*)(lds + L_LB + (p ^ 1) * 8192);  // base(t-1) -> base(t+1)

    // ===== PHASE 1: h_t @ [Rzr|Ro] =====
    // issue h poll round 0 + A(t+1)/kcp/ch prefetch; single first drain
    f16x8 sh[4];
    const char* pH = wsb + WS_HHI + (size_t)row0 * 2048;
    #pragma unroll
    for (int it = 0; it < 4; ++it) gload_x4(sh[it], pH + it * 8192 + tid * 16);
    const bool havA = (t + 1 < T_);
    f16x8 av;
    if (havA) {
      av = *(const f16x8*)(Ap + ((size_t)(row0 + (tid >> 5)) * T_ + (t + 1)) * 256 + (tid & 31) * 8);
      #pragma unroll
      for (int e = 0; e < 4; ++e) kcv[e] = kcp[(size_t)chreg[e] * 4096 + bcolw];
      if (t + 2 < T_) {
        #pragma unroll
        for (int e = 0; e < 4; ++e)
          chreg[e] = chp[(size_t)(row0 + kc * 4 + e) * T_ + (t + 2)];
      }
    }
    {
      bool ok0 = false, ok1 = false, ok2 = false, ok3 = false;
      for (int rounds = 0; ; ) {
        vwait0();
        ok0 = ok0 || chunk_ok(sh[0], htag);
        ok1 = ok1 || chunk_ok(sh[1], htag);
        ok2 = ok2 || chunk_ok(sh[2], htag);
        ok3 = ok3 || chunk_ok(sh[3], htag);
        if (ok0 & ok1 & ok2 & ok3) break;
        if (++rounds >= POLL_BOUND) break;
        if (!ok0) gload_x4(sh[0], pH + 0 * 8192 + tid * 16);
        if (!ok1) gload_x4(sh[1], pH + 1 * 8192 + tid * 16);
        if (!ok2) gload_x4(sh[2], pH + 2 * 8192 + tid * 16);
        if (!ok3) gload_x4(sh[3], pH + 3 * 8192 + tid * 16);
      }
    }
    // LDS-write staged h (swizzle here; global stays linear)
    #pragma unroll
    for (int it = 0; it < 4; ++it) {
      const int g = it * 8192 + tid * 16;
      const int r = g >> 11, cb = g & 2047;
      *(f16x8*)(lds + L_STHI + r * 2048 + (cb ^ ((r & 7) << 4))) = sh[it];
    }
    if (havA)
      *(f16x8*)(lds + L_ABUF + (tid >> 5) * 512 + (((tid & 31) * 16) ^ (((tid >> 5) & 7) << 4))) = av;
    __syncthreads();

    // main MFMA: 24 per wave
    f32x4 acc[3] = {{0,0,0,0},{0,0,0,0},{0,0,0,0}};
    {
      const int hb = lcol * 2048, hsw = (lcol & 7) << 4;
      #pragma unroll
      for (int j = 0; j < 8; ++j) {
        f16x8 a = *(f16x8*)(lds + L_STHI + hb + (((kq * 8 + j) * 64 + kc * 16) ^ hsw));
        #pragma unroll
        for (int q = 0; q < 3; ++q) acc[q] = MFMA16(a, Bp1[q][j], acc[q]);
      }
    }
    #pragma unroll
    for (int q = 0; q < 3; ++q)
      #pragma unroll
      for (int e = 0; e < 4; ++e)
        *(float*)(lds + EXT(kq, chh, q) + e * 260 + (kc * 16 + lcol) * 4) = acc[q][e];
    __syncthreads();

    // reduce: vz, vr, vo for element (rm, 16rch+rl)
    float vz = 0.f, vr = 0.f, vo = 0.f;
    {
      const int off = (rm & 3) * 260 + ((rm >> 2) * 16 + rl) * 4;
      #pragma unroll
      for (int k2 = 0; k2 < 4; ++k2) {
        vz += *(float*)(lds + EXT(k2, rch, 0) + off);
        vr += *(float*)(lds + EXT(k2, rch, 1) + off);
        vo += *(float*)(lds + EXT(k2, rch, 2) + off);
      }
    }
    const float obase = LBq[(rm * 4 + 3) * 32 + 16 * rch + rl];  // base_o(t-1)
    if (t == T_) {
      out[((size_t)(row0 + rm) * T_ + (t - 1)) * U_ + rucol] = tanhf(vo + obase);
      break;
    }
    // z -> LDS, tagged r*h -> pack buffer
    {
      ((float*)(lds + L_Z))[rm * 32 + 16 * rch + rl] =
          sigm(vz + LBp[(rm * 4 + 0) * 32 + 16 * rch + rl]);
      const float rv = sigm(vr + LBp[(rm * 4 + 1) * 32 + 16 * rch + rl]);
      const float hv = (float)*(f16*)(lds + L_STHI + rm * 2048 + ((2 * rucol) ^ ((rm & 7) << 4)));
      *(unsigned short*)(lds + L_PACK + rm * 64 + (16 * rch + rl) * 2) = tag16(rv * hv, ntag);
    }
    __syncthreads();
    // wave 0: coalesced rh store (no drain, no flag — tags carry readiness)
    if (wid == 0) {
      f16x8 pv = *(f16x8*)(lds + L_PACK + (lane >> 2) * 64 + (lane & 3) * 16);
      gstore_x4(wsb + WS_RH + (size_t)(row0 + (lane >> 2)) * 2048 + c * 64 + (lane & 3) * 16, pv);
    }
    // issue phase-2 poll round 0 + Rh B fragments, then hide visibility under gap work
    f16x8 sr[4], b2[8];
    const char* pR = wsb + WS_RH + (size_t)row0 * 2048;
    #pragma unroll
    for (int it = 0; it < 4; ++it) gload_x4(sr[it], pR + it * 8192 + tid * 16);
    {
      const f16* wp2 = wT + (size_t)(2048 + 32 * c + 16 * chh + lcol) * 1024;
      #pragma unroll
      for (int j = 0; j < 8; ++j) b2[j] = *(const f16x8*)(wp2 + (kq * 8 + j) * 32 + kc * 8);
    }
    // GAP: o(t-1) out store + base(t+1) MFMA
    if (t > 0) out[((size_t)(row0 + rm) * T_ + (t - 1)) * U_ + rucol] = tanhf(vo + obase);
    if (havA) {
      f32x4 ab = {0.f, 0.f, 0.f, 0.f};
      #pragma unroll
      for (int j = 0; j < 8; ++j) {
        f16x8 a = *(f16x8*)(lds + L_ABUF + lcol * 512 + ((j * 64 + kc * 16) ^ ((lcol & 7) << 4)));
        ab = MFMA16(a, BpB[j], ab);
      }
      #pragma unroll
      for (int e = 0; e < 4; ++e)
        LBq[((kc * 4 + e) * 4 + wreg) * 32 + 16 * wch + lcol] = ab[e] + kcv[e] + biasv;
    }
    // ===== PHASE 2: (r*h) @ Rh =====
    {
      bool ok0 = false, ok1 = false, ok2 = false, ok3 = false;
      for (int rounds = 0; ; ) {
        vwait0();
        ok0 = ok0 || chunk_ok(sr[0], ntag);
        ok1 = ok1 || chunk_ok(sr[1], ntag);
        ok2 = ok2 || chunk_ok(sr[2], ntag);
        ok3 = ok3 || chunk_ok(sr[3], ntag);
        if (ok0 & ok1 & ok2 & ok3) break;
        if (++rounds >= POLL_BOUND) break;
        if (!ok0) gload_x4(sr[0], pR + 0 * 8192 + tid * 16);
        if (!ok1) gload_x4(sr[1], pR + 1 * 8192 + tid * 16);
        if (!ok2) gload_x4(sr[2], pR + 2 * 8192 + tid * 16);
        if (!ok3) gload_x4(sr[3], pR + 3 * 8192 + tid * 16);
      }
    }
    #pragma unroll
    for (int it = 0; it < 4; ++it) {
      const int g = it * 8192 + tid * 16;
      const int r = g >> 11, cb = g & 2047;
      *(f16x8*)(lds + L_STHI + r * 2048 + (cb ^ ((r & 7) << 4))) = sr[it];
    }
    __syncthreads();
    f32x4 a2 = {0.f, 0.f, 0.f, 0.f};
    {
      const int hb = lcol * 2048, hsw = (lcol & 7) << 4;
      #pragma unroll
      for (int j = 0; j < 8; ++j) {
        f16x8 a = *(f16x8*)(lds + L_STHI + hb + (((kq * 8 + j) * 64 + kc * 16) ^ hsw));
        a2 = MFMA16(a, b2[j], a2);
      }
    }
    #pragma unroll
    for (int e = 0; e < 4; ++e)
      *(float*)(lds + EXT(kq, chh, 0) + e * 260 + (kc * 16 + lcol) * 4) = a2[e];
    __syncthreads();
    // h update (1 elem/thread); tagged pack
    {
      const int off = (rm & 3) * 260 + ((rm >> 2) * 16 + rl) * 4;
      float v = 0.f;
      #pragma unroll
      for (int k2 = 0; k2 < 4; ++k2) v += *(float*)(lds + EXT(k2, rch, 0) + off);
      const float hh = tanhf(v + LBp[(rm * 4 + 2) * 32 + 16 * rch + rl]);
      const float zv = ((float*)(lds + L_Z))[rm * 32 + 16 * rch + rl];
      h_own = zv * h_own + (1.f - zv) * hh;
      *(unsigned short*)(lds + L_PACK + rm * 64 + (16 * rch + rl) * 2) = tag16(h_own, ntag);
    }
    __syncthreads();
    if (wid == 0) {
      f16x8 pv = *(f16x8*)(lds + L_PACK + (lane >> 2) * 64 + (lane & 3) * 16);
      gstore_x4(wsb + WS_HHI + (size_t)(row0 + (lane >> 2)) * 2048 + c * 64 + (lane & 3) * 16, pv);
    }
  }
}

extern "C" void kernel_launch(void* const* d_in, const int* in_sizes, int n_in,
                              void* d_out, int out_size, void* d_ws, size_t ws_size,
                              hipStream_t stream) {
  const float* x    = (const float*)d_in[0];
  const int*   ch   = (const int*)d_in[1];
  const float* Wd   = (const float*)d_in[2];
  const float* bd_  = (const float*)d_in[3];
  const float* Ws   = (const float*)d_in[4];
  const float* bs_  = (const float*)d_in[5];
  const float* rk   = (const float*)d_in[6];
  const float* kc_  = (const float*)d_in[7];
  const float* kd   = (const float*)d_in[8];
  const float* ks   = (const float*)d_in[9];
  const float* bias = (const float*)d_in[10];
  char* wsb = (char*)d_ws;
  float* out = (float*)d_out;
  if (ws_size < (size_t)WS_END) return;

  // zero h/rh planes: h_0 = 0 with tag 0 (= valid for t=0); rh tag 0 (= invalid for t=0)
  hipMemsetAsync(wsb, 0, WS_WT, stream);
  prep_kernel<<<20480, 256, 0, stream>>>(rk, kd, ks,
      (f16*)(wsb + WS_WT), (f16*)(wsb + WS_KDT), (f16*)(wsb + WS_KST));
  acum_kernel<<<128, 64, 0, stream>>>(x, Wd, bd_, Ws, bs_, (f16*)(wsb + WS_A));
  hipFuncSetAttribute((const void*)sgru_kernel,
                      hipFuncAttributeMaxDynamicSharedMemorySize, LDS_SZ);
  sgru_kernel<<<256, 512, LDS_SZ, stream>>>(ch, kc_, bias, wsb, out);
}

// Round 10
// 1946.863 us; speedup vs baseline: 1.3702x; 1.3702x over previous
//
#include <hip/hip_runtime.h>
#include <cstdint>
#include <cstddef>

typedef _Float16 f16;
typedef _Float16 f16x8 __attribute__((ext_vector_type(8)));
typedef float f32x4 __attribute__((ext_vector_type(4)));

#define T_  256
#define U_  1024

// ---- workspace offsets (bytes) ----
#define WS_FLA  0u                        // flagsA[256]
#define WS_FLB  1024u                     // flagsB[256]
#define WS_HHI  4096u                     // h plane [128][1024] f16, LINEAR
#define WS_RH   266240u                   // rh plane [128][1024] f16, LINEAR
#define WS_WT   528384u                   // recurrent_kernel^T f16 [4096][1024]
#define WS_KDT  8916992u                  // kernel_d^T f16 [4096][128]
#define WS_KST  9965568u                  // kernel_s^T f16 [4096][128]
#define WS_A    11014144u                 // A [128][256][256] f16
#define WS_END  27791360u

// ---- LDS ----
#define L_STHI 0        // staged h (rh in ph2): [16][2048B], swizzled at LDS-write
#define L_ABUF 32768    // A(t+1) slice [16][512B] swizzled
#define L_EXCH 40960    // 24 tiles x 1040B
#define L_Z    65920    // [16][32] f32
#define L_LB   67968    // base dbuf: 2 x [16 rows][4 reg][32 cols] f32
#define L_PACK 84352    // 1KB pack buffer [16 rows][64B]
#define LDS_SZ 85376
#define EXT(kq,ch,q) (L_EXCH + (((kq)*2+(ch))*3+(q))*1040)

#define SPIN_BOUND 65536

#define MFMA16(a,b,c) __builtin_amdgcn_mfma_f32_16x16x32_f16((a),(b),(c),0,0,0)
__device__ __forceinline__ float sigm(float v) { return 1.0f / (1.0f + __expf(-v)); }
__device__ __forceinline__ void vwait0() { asm volatile("s_waitcnt vmcnt(0)" ::: "memory"); }

// ---- system-scope (MALL coherence point) ops — the PROVEN substrate ----
__device__ __forceinline__ void gload_x4(f16x8& d, const void* p) {
  asm volatile("global_load_dwordx4 %0, %1, off sc0 sc1" : "=&v"(d) : "v"(p));
}
__device__ __forceinline__ void gstore_x4(void* p, f16x8 v) {
  asm volatile("global_store_dwordx4 %0, %1, off sc0 sc1" :: "v"(p), "v"(v) : "memory");
}
__device__ __forceinline__ unsigned gload_flag(const unsigned* p) {
  unsigned v;
  asm volatile("global_load_dword %0, %1, off sc0 sc1\n\ts_waitcnt vmcnt(0)"
               : "=&v"(v) : "v"(p) : "memory");
  return v;
}
__device__ __forceinline__ void gstore_flag(unsigned* p, unsigned v) {
  asm volatile("global_store_dword %0, %1, off sc0 sc1" :: "v"(p), "v"(v) : "memory");
}
__device__ __forceinline__ void bar_wait(unsigned* flags, int rg, unsigned target, int tid) {
  if (tid < 64) {
    const unsigned* f = flags + rg * 32 + (tid & 31);
    int it = 0;
    while (gload_flag(f) < target && ++it < SPIN_BOUND) __builtin_amdgcn_s_sleep(1);
  }
  __builtin_amdgcn_fence(__ATOMIC_ACQUIRE, "workgroup");
  __syncthreads();
}

// ---------- prep: weight transposes ----------
__global__ __launch_bounds__(256) void prep_kernel(const float* __restrict__ rk,
                                                   const float* __restrict__ kd,
                                                   const float* __restrict__ ks,
                                                   f16* __restrict__ wT,
                                                   f16* __restrict__ kdT,
                                                   f16* __restrict__ ksT) {
  size_t i = (size_t)blockIdx.x * 256 + threadIdx.x;
  if (i < 4194304u) {
    int k = (int)(i >> 12), n = (int)(i & 4095);
    wT[(size_t)n * 1024 + k] = (f16)rk[i];
  } else if (i < 4718592u) {
    size_t j = i - 4194304u;
    int k = (int)(j >> 12), n = (int)(j & 4095);
    kdT[(size_t)n * 128 + k] = (f16)kd[j];
  } else {
    size_t j = i - 4718592u;
    int k = (int)(j >> 12), n = (int)(j & 4095);
    ksT[(size_t)n * 128 + k] = (f16)ks[j];
  }
}

// ---------- prep: A = [tanh(d@Wd+bd) | tanh(s@Ws+bs)], d = cumsum ----------
__global__ __launch_bounds__(64) void acum_kernel(const float* __restrict__ x,
    const float* __restrict__ Wd, const float* __restrict__ bd,
    const float* __restrict__ Ws, const float* __restrict__ bs,
    f16* __restrict__ A) {
  const int b = blockIdx.x, lane = threadIdx.x;
  float w0[4], w1[4], w2[4], bb[4];
  #pragma unroll
  for (int q = 0; q < 4; ++q) {
    int col = lane + 64 * q;
    if (col < 128) { w0[q] = Wd[col]; w1[q] = Wd[128 + col]; w2[q] = 0.f; bb[q] = bd[col]; }
    else { int c2 = col - 128; w0[q] = Ws[c2]; w1[q] = Ws[128 + c2]; w2[q] = Ws[256 + c2]; bb[q] = bs[c2]; }
  }
  float d0 = 0.f, d1 = 0.f;
  for (int t = 0; t < T_; ++t) {
    const float* xp = x + ((size_t)b * T_ + t) * 5;
    float x0 = xp[0], x1 = xp[1], x2 = xp[2], x3 = xp[3], x4 = xp[4];
    d0 += x0; d1 += x1;
    f16* Ap = A + ((size_t)b * T_ + t) * 256;
    #pragma unroll
    for (int q = 0; q < 4; ++q) {
      int col = lane + 64 * q;
      float v = (col < 128) ? tanhf(d0 * w0[q] + d1 * w1[q] + bb[q])
                            : tanhf(x2 * w0[q] + x3 * w1[q] + x4 * w2[q] + bb[q]);
      Ap[col] = (f16)v;
    }
  }
}

// ---------- persistent SGRU: 256 blocks = 8 rg (16 rows) x 32 c (32 cols/region) ----------
__global__ __launch_bounds__(512, 2) void sgru_kernel(
    const int* __restrict__ chp, const float* __restrict__ kcp,
    const float* __restrict__ bias, char* __restrict__ wsb,
    float* __restrict__ out) {
  extern __shared__ char lds[];
  const int tid  = threadIdx.x;
  const int wid  = tid >> 6;
  const int lane = tid & 63;
  const int lcol = lane & 15;
  const int kc   = lane >> 4;
  const int lin  = blockIdx.x;
  const int rg   = lin >> 5;
  const int c    = lin & 31;
  const int row0 = rg * 16;
  const int kq   = wid >> 1;        // k-quarter 0..3
  const int chh  = wid & 1;         // 16-col half 0..1
  // reduce mapping: 512 threads -> (rch, rm, rl)
  const int rp = tid & 255, rm = rp >> 4, rl = rp & 15, rch = tid >> 8;
  const int rucol = 32 * c + 16 * rch + rl;
  // base tile per wave
  const int wreg = wid >> 1, wch = wid & 1;
  const int bcolw = wreg * 1024 + 32 * c + 16 * wch + lcol;

  const f16* __restrict__ wT  = (const f16*)(wsb + WS_WT);
  const f16* __restrict__ kdT = (const f16*)(wsb + WS_KDT);
  const f16* __restrict__ ksT = (const f16*)(wsb + WS_KST);
  const f16* __restrict__ Ap  = (const f16*)(wsb + WS_A);
  unsigned* flagsA = (unsigned*)(wsb + WS_FLA);
  unsigned* flagsB = (unsigned*)(wsb + WS_FLB);

  // ---- resident B fragments: [Rzr|Ro] (3 regions) + Rh + base kdT/ksT ----
  f16x8 Bp1[3][8], Bp2[8], BpB[8];
  #pragma unroll
  for (int q = 0; q < 3; ++q) {
    const int orig = (q == 2 ? 3072 : q * 1024) + 32 * c + 16 * chh + lcol;
    const f16* wp = wT + (size_t)orig * 1024;
    #pragma unroll
    for (int j = 0; j < 8; ++j)
      Bp1[q][j] = *(const f16x8*)(wp + (kq * 8 + j) * 32 + kc * 8);
  }
  {
    const f16* wp2 = wT + (size_t)(2048 + 32 * c + 16 * chh + lcol) * 1024;
    #pragma unroll
    for (int j = 0; j < 8; ++j) Bp2[j] = *(const f16x8*)(wp2 + (kq * 8 + j) * 32 + kc * 8);
  }
  #pragma unroll
  for (int j = 0; j < 8; ++j)
    BpB[j] = (j < 4) ? *(const f16x8*)(kdT + (size_t)bcolw * 128 + j * 32 + kc * 8)
                     : *(const f16x8*)(ksT + (size_t)bcolw * 128 + (j - 4) * 32 + kc * 8);
  const float biasv = bias[bcolw];
  float h_own = 0.f;
  int chreg[4]; float kcv[4];

  // ---- pre-loop: stage A(0); kc(0) gathers; chreg = ch(1); base(0) -> LB[0] ----
  {
    f16x8 av = *(const f16x8*)(Ap + ((size_t)(row0 + (tid >> 5)) * T_ + 0) * 256 + (tid & 31) * 8);
    *(f16x8*)(lds + L_ABUF + (tid >> 5) * 512 + (((tid & 31) * 16) ^ (((tid >> 5) & 7) << 4))) = av;
  }
  #pragma unroll
  for (int e = 0; e < 4; ++e) {
    const size_t r = (size_t)(row0 + kc * 4 + e) * T_;
    kcv[e] = kcp[(size_t)chp[r] * 4096 + bcolw];
    chreg[e] = chp[r + 1];
  }
  __syncthreads();
  {
    f32x4 ab = {0.f, 0.f, 0.f, 0.f};
    #pragma unroll
    for (int j = 0; j < 8; ++j) {
      f16x8 a = *(f16x8*)(lds + L_ABUF + lcol * 512 + ((j * 64 + kc * 16) ^ ((lcol & 7) << 4)));
      ab = MFMA16(a, BpB[j], ab);
    }
    float* lb0 = (float*)(lds + L_LB);
    #pragma unroll
    for (int e = 0; e < 4; ++e)
      lb0[((kc * 4 + e) * 4 + wreg) * 32 + 16 * wch + lcol] = ab[e] + kcv[e] + biasv;
  }
  __syncthreads();

  for (int t = 0; ; ++t) {
    const int p = t & 1;
    float* LBp = (float*)(lds + L_LB + p * 8192);        // base(t)
    float* LBq = (float*)(lds + L_LB + (p ^ 1) * 8192);  // base(t-1) -> base(t+1)

    // ===== stage h(t) (+ A(t+1) in parallel) — ONLY these drain here =====
    f16x8 sh[4];
    const char* pH = wsb + WS_HHI + (size_t)row0 * 2048;
    #pragma unroll
    for (int it = 0; it < 4; ++it) gload_x4(sh[it], pH + it * 8192 + tid * 16);
    const bool havA = (t + 1 < T_);
    f16x8 av;
    if (havA)
      av = *(const f16x8*)(Ap + ((size_t)(row0 + (tid >> 5)) * T_ + (t + 1)) * 256 + (tid & 31) * 8);
    vwait0();
    #pragma unroll
    for (int it = 0; it < 4; ++it) {
      const int g = it * 8192 + tid * 16;
      const int r = g >> 11, cb = g & 2047;
      *(f16x8*)(lds + L_STHI + r * 2048 + (cb ^ ((r & 7) << 4))) = sh[it];
    }
    __syncthreads();

    // ===== P1 CRITICAL: r tile only -> pack -> store -> flag =====
    if (t < T_) {
      f32x4 accr = {0.f, 0.f, 0.f, 0.f};
      {
        const int hb = lcol * 2048, hsw = (lcol & 7) << 4;
        #pragma unroll
        for (int j = 0; j < 8; ++j) {
          f16x8 a = *(f16x8*)(lds + L_STHI + hb + (((kq * 8 + j) * 64 + kc * 16) ^ hsw));
          accr = MFMA16(a, Bp1[1][j], accr);
        }
      }
      #pragma unroll
      for (int e = 0; e < 4; ++e)
        *(float*)(lds + EXT(kq, chh, 1) + e * 260 + (kc * 16 + lcol) * 4) = accr[e];
      __syncthreads();
      {
        const int off = (rm & 3) * 260 + ((rm >> 2) * 16 + rl) * 4;
        float vr = 0.f;
        #pragma unroll
        for (int k2 = 0; k2 < 4; ++k2) vr += *(float*)(lds + EXT(k2, rch, 1) + off);
        const float rv = sigm(vr + LBp[(rm * 4 + 1) * 32 + 16 * rch + rl]);
        const float hv = (float)*(f16*)(lds + L_STHI + rm * 2048 + ((2 * rucol) ^ ((rm & 7) << 4)));
        *(f16*)(lds + L_PACK + rm * 64 + (16 * rch + rl) * 2) = (f16)(rv * hv);
      }
      __syncthreads();
      if (wid == 0) {
        f16x8 pv = *(f16x8*)(lds + L_PACK + (lane >> 2) * 64 + (lane & 3) * 16);
        gstore_x4(wsb + WS_RH + (size_t)(row0 + (lane >> 2)) * 2048 + c * 64 + (lane & 3) * 16, pv);
        vwait0();
        if (lane == 0) gstore_flag(flagsA + lin, (unsigned)(t + 1));
      }
    }

    // ===== GAP-A (hidden behind barrier A): z, o tiles; A/kcp prefetch; base(t+1) =====
    f32x4 accz = {0.f, 0.f, 0.f, 0.f}, acco = {0.f, 0.f, 0.f, 0.f};
    {
      const int hb = lcol * 2048, hsw = (lcol & 7) << 4;
      #pragma unroll
      for (int j = 0; j < 8; ++j) {
        f16x8 a = *(f16x8*)(lds + L_STHI + hb + (((kq * 8 + j) * 64 + kc * 16) ^ hsw));
        if (t < T_) accz = MFMA16(a, Bp1[0][j], accz);
        acco = MFMA16(a, Bp1[2][j], acco);
      }
    }
    #pragma unroll
    for (int e = 0; e < 4; ++e) {
      if (t < T_)
        *(float*)(lds + EXT(kq, chh, 0) + e * 260 + (kc * 16 + lcol) * 4) = accz[e];
      *(float*)(lds + EXT(kq, chh, 2) + e * 260 + (kc * 16 + lcol) * 4) = acco[e];
    }
    if (havA) {
      *(f16x8*)(lds + L_ABUF + (tid >> 5) * 512 + (((tid & 31) * 16) ^ (((tid >> 5) & 7) << 4))) = av;
      #pragma unroll
      for (int e = 0; e < 4; ++e) kcv[e] = kcp[(size_t)chreg[e] * 4096 + bcolw];  // drains in P2
      if (t + 2 < T_) {
        #pragma unroll
        for (int e = 0; e < 4; ++e)
          chreg[e] = chp[(size_t)(row0 + kc * 4 + e) * T_ + (t + 2)];
      }
    }
    __syncthreads();
    {
      const int off = (rm & 3) * 260 + ((rm >> 2) * 16 + rl) * 4;
      float vz = 0.f, vo = 0.f;
      #pragma unroll
      for (int k2 = 0; k2 < 4; ++k2) {
        if (t < T_) vz += *(float*)(lds + EXT(k2, rch, 0) + off);
        vo += *(float*)(lds + EXT(k2, rch, 2) + off);
      }
      const float obase = LBq[(rm * 4 + 3) * 32 + 16 * rch + rl];  // base_o(t-1)
      if (t > 0) out[((size_t)(row0 + rm) * T_ + (t - 1)) * U_ + rucol] = tanhf(vo + obase);
      if (t < T_)
        ((float*)(lds + L_Z))[rm * 32 + 16 * rch + rl] =
            sigm(vz + LBp[(rm * 4 + 0) * 32 + 16 * rch + rl]);
    }
    if (t == T_) break;
    __syncthreads();      // obase reads done before LBq overwrite
    if (havA) {
      f32x4 ab = {0.f, 0.f, 0.f, 0.f};
      #pragma unroll
      for (int j = 0; j < 8; ++j) {
        f16x8 a = *(f16x8*)(lds + L_ABUF + lcol * 512 + ((j * 64 + kc * 16) ^ ((lcol & 7) << 4)));
        ab = MFMA16(a, BpB[j], ab);
      }
      #pragma unroll
      for (int e = 0; e < 4; ++e)
        LBq[((kc * 4 + e) * 4 + wreg) * 32 + 16 * wch + lcol] = ab[e] + biasv;  // +kcv in P2
    }
    bar_wait(flagsA, rg, (unsigned)(t + 1), tid);

    // ===== P2 CRITICAL: stage rh -> hh -> h update -> pack -> store -> flag =====
    f16x8 sr[4];
    const char* pR = wsb + WS_RH + (size_t)row0 * 2048;
    #pragma unroll
    for (int it = 0; it < 4; ++it) gload_x4(sr[it], pR + it * 8192 + tid * 16);
    vwait0();     // drains rh + GAP-A's kcp/out stragglers
    #pragma unroll
    for (int it = 0; it < 4; ++it) {
      const int g = it * 8192 + tid * 16;
      const int r = g >> 11, cb = g & 2047;
      *(f16x8*)(lds + L_STHI + r * 2048 + (cb ^ ((r & 7) << 4))) = sr[it];
    }
    __syncthreads();
    f32x4 a2 = {0.f, 0.f, 0.f, 0.f};
    {
      const int hb = lcol * 2048, hsw = (lcol & 7) << 4;
      #pragma unroll
      for (int j = 0; j < 8; ++j) {
        f16x8 a = *(f16x8*)(lds + L_STHI + hb + (((kq * 8 + j) * 64 + kc * 16) ^ hsw));
        a2 = MFMA16(a, Bp2[j], a2);
      }
    }
    #pragma unroll
    for (int e = 0; e < 4; ++e)
      *(float*)(lds + EXT(kq, chh, 0) + e * 260 + (kc * 16 + lcol) * 4) = a2[e];
    if (havA) {   // lazy kcv add into base(t+1) (kcv drained by this phase's vwait0)
      #pragma unroll
      for (int e = 0; e < 4; ++e)
        LBq[((kc * 4 + e) * 4 + wreg) * 32 + 16 * wch + lcol] += kcv[e];
    }
    __syncthreads();
    {
      const int off = (rm & 3) * 260 + ((rm >> 2) * 16 + rl) * 4;
      float v = 0.f;
      #pragma unroll
      for (int k2 = 0; k2 < 4; ++k2) v += *(float*)(lds + EXT(k2, rch, 0) + off);
      const float hh = tanhf(v + LBp[(rm * 4 + 2) * 32 + 16 * rch + rl]);
      const float zv = ((float*)(lds + L_Z))[rm * 32 + 16 * rch + rl];
      h_own = zv * h_own + (1.f - zv) * hh;
      *(f16*)(lds + L_PACK + rm * 64 + (16 * rch + rl) * 2) = (f16)h_own;
    }
    __syncthreads();
    if (wid == 0) {
      f16x8 pv = *(f16x8*)(lds + L_PACK + (lane >> 2) * 64 + (lane & 3) * 16);
      gstore_x4(wsb + WS_HHI + (size_t)(row0 + (lane >> 2)) * 2048 + c * 64 + (lane & 3) * 16, pv);
      vwait0();
      if (lane == 0) gstore_flag(flagsB + lin, (unsigned)(t + 1));
    }
    bar_wait(flagsB, rg, (unsigned)(t + 1), tid);
  }
}

extern "C" void kernel_launch(void* const* d_in, const int* in_sizes, int n_in,
                              void* d_out, int out_size, void* d_ws, size_t ws_size,
                              hipStream_t stream) {
  const float* x    = (const float*)d_in[0];
  const int*   ch   = (const int*)d_in[1];
  const float* Wd   = (const float*)d_in[2];
  const float* bd_  = (const float*)d_in[3];
  const float* Ws   = (const float*)d_in[4];
  const float* bs_  = (const float*)d_in[5];
  const float* rk   = (const float*)d_in[6];
  const float* kc_  = (const float*)d_in[7];
  const float* kd   = (const float*)d_in[8];
  const float* ks   = (const float*)d_in[9];
  const float* bias = (const float*)d_in[10];
  char* wsb = (char*)d_ws;
  float* out = (float*)d_out;
  if (ws_size < (size_t)WS_END) return;

  // zero flags + h/rh planes (h_0 = 0)
  hipMemsetAsync(wsb, 0, WS_WT, stream);
  prep_kernel<<<20480, 256, 0, stream>>>(rk, kd, ks,
      (f16*)(wsb + WS_WT), (f16*)(wsb + WS_KDT), (f16*)(wsb + WS_KST));
  acum_kernel<<<128, 64, 0, stream>>>(x, Wd, bd_, Ws, bs_, (f16*)(wsb + WS_A));
  hipFuncSetAttribute((const void*)sgru_kernel,
                      hipFuncAttributeMaxDynamicSharedMemorySize, LDS_SZ);
  sgru_kernel<<<256, 512, LDS_SZ, stream>>>(ch, kc_, bias, wsb, out);
}